// Round 14
// baseline (165.892 us; speedup 1.0000x reference)
//
#include <hip/hip_runtime.h>

#define B_   128
#define L_   196
#define ENC_ 2048
#define DEC_ 512
#define ATT_ 512
#define M_   (B_ * L_)   // 25088

typedef _Float16 f16x4 __attribute__((ext_vector_type(4)));
typedef _Float16 f16x8 __attribute__((ext_vector_type(8)));
typedef __fp16   h16x2 __attribute__((ext_vector_type(2)));
typedef float    f32x4 __attribute__((ext_vector_type(4)));

// Raw barrier: order LDS ops (lgkmcnt) but do NOT drain vmcnt -> global
// prefetches stay in flight across the barrier.
#define FENCE_LDS_BARRIER()                                        \
    do {                                                           \
        asm volatile("s_waitcnt lgkmcnt(0)" ::: "memory");         \
        __builtin_amdgcn_s_barrier();                              \
        __builtin_amdgcn_sched_barrier(0);                         \
    } while (0)

// ---------------- ws layout ----------------
// [0,          262144)   dec_map  f32 [128][512]
// [262144,    2359296)   WeTs     f16 tiled: [ntile=4][kt=64][k8=4][row=128] x f16x8 unit
// [2359296,   2760704)   partial  f32 [4][25088]

// We [2048][512] fp32 -> WeTs tiled-f16. Unit (nt,kt,k8,row) holds
// We[kt*32+k8*8+j][nt*128+row] for j=0..7.
__global__ void wets_kernel(const float* __restrict__ We, _Float16* __restrict__ WeTs) {
    int u = blockIdx.x * 256 + threadIdx.x;     // 131072 units
    int row = u & 127;
    int k8  = (u >> 7) & 3;
    int kt  = (u >> 9) & 63;
    int nt  = u >> 15;
    int n  = nt * 128 + row;
    int k0 = kt * 32 + k8 * 8;
    f16x8 h;
#pragma unroll
    for (int j = 0; j < 8; ++j) h[j] = (_Float16)We[(k0 + j) * ATT_ + n];
    *reinterpret_cast<f16x8*>(WeTs + (size_t)u * 8) = h;
}

// dec_map[b][a] = decoder_hidden[b] . Wd[:,a] + bd[a]
__global__ void decmap_kernel(const float* __restrict__ dh, const float* __restrict__ Wd,
                              const float* __restrict__ bd, float* __restrict__ dec) {
    int b = blockIdx.x;       // 128
    int a = threadIdx.x;      // 512
    float acc = bd[a];
    const float* dhp = dh + b * DEC_;
#pragma unroll 8
    for (int k = 0; k < DEC_; ++k) acc += dhp[k] * Wd[k * ATT_ + a];
    dec[b * ATT_ + a] = acc;
}

// Fused GEMM: 128x128 tile, BK=32. 3-deep A pipeline (areg0/1/2 + 3 LDS bufs),
// 2-deep B reg pipeline (bf0/1 from L2-resident WeTs). VMEM ISSUE ORDER IS
// B-FIRST-THEN-A, pinned by sched_barrier(0): vmcnt drains are in-order, so
// the MFMA's wait-for-B must not transitively wait for A loads issued in the
// same phase (that coupling nullified all prefetch depth in R8-R13 -> every
// phase paid full HBM latency, ~2360cy/phase). With B-first: B has 1 phase of
// slack (L2 ~200cy), A has 2 phases (~HBM latency). lgkm-only barriers.
// launch_bounds(256,3): unified VGPR/AGPR file; 64 acc + ~90 arch needs the
// 170 cap. (256,4) caps at 128 -> catastrophic spill (R7/R10). DO NOT raise.
__global__ __launch_bounds__(256, 3)
void gemm_score_kernel(const float* __restrict__ enc,
                       const _Float16* __restrict__ WeTs,
                       const float* __restrict__ be,
                       const float* __restrict__ wa,
                       const float* __restrict__ dec,
                       float* __restrict__ partial) {
    __shared__ _Float16 smem[3][4096];   // A: [buf][(k8*128+row)*8], 8KB each
    __shared__ float red[2][128];

    // XCD-chunked swizzle: 4 ntile-siblings of one mtile stay on one XCD.
    int bid = blockIdx.x;
    int sid = (bid & 7) * 98 + (bid >> 3);           // bijective on [0,784)
    int mtile = sid >> 2;                            // 0..195
    int ntile = sid & 3;                             // 0..3

    int tid  = threadIdx.x;
    int lane = tid & 63, wid = tid >> 6;
    int wm = wid >> 1, wn = wid & 1;                 // 2x2 waves of 64x64
    int l15 = lane & 15, lg = lane >> 4;

    // A staging: thread -> (row = tid>>2 (+64), c8 = tid&3)
    int arowi = tid >> 2;                            // 0..63
    int ac8   = tid & 3;
    const float* agA = enc + (size_t)(mtile * 128 + arowi) * ENC_ + ac8 * 8;
    const float* agB = agA + (size_t)64 * ENC_;
    int wa0 = (ac8 * 128 + (arowi ^ (2 * ac8))) * 8;   // swizzled A unit
    int wa1 = wa0 + 64 * 8;

    // B fragment source: WeTs unit (ntile, kt, k8=lg, row=wn*64+ni*16+l15)
    const _Float16* bfr = WeTs +
        ((size_t)ntile * 64 * 4 * 128 + (size_t)lg * 128 + wn * 64 + l15) * 8;
    // per-kt stride in halves: 4*128*8 = 4096

    // A frag read half-offsets
    int afo = (lg * 128 + wm * 64 + (l15 ^ (2 * lg))) * 8;   // A swizzled

    // staging register sets — statically named (rule #20)
    float4 areg0[4], areg1[4], areg2[4];
    f16x8  bf0[4], bf1[4];

    f32x4 acc[4][4];
#pragma unroll
    for (int mi = 0; mi < 4; ++mi)
#pragma unroll
        for (int ni = 0; ni < 4; ++ni) acc[mi][ni] = (f32x4){0.f, 0.f, 0.f, 0.f};

#define DEF_LOADA(S)                                                     \
    auto loadA##S = [&](int kt) {                                        \
        const float* a0 = agA + kt * 32;                                 \
        const float* a1 = agB + kt * 32;                                 \
        areg##S[0] = *reinterpret_cast<const float4*>(a0);               \
        areg##S[1] = *reinterpret_cast<const float4*>(a0 + 4);           \
        areg##S[2] = *reinterpret_cast<const float4*>(a1);               \
        areg##S[3] = *reinterpret_cast<const float4*>(a1 + 4);           \
    }
    DEF_LOADA(0); DEF_LOADA(1); DEF_LOADA(2);
#undef DEF_LOADA

#define DEF_LOADB(S)                                                     \
    auto loadB##S = [&](int kt) {                                        \
        const _Float16* s = bfr + (size_t)kt * 4096;                     \
        bf##S[0] = *reinterpret_cast<const f16x8*>(s + 0 * 128);         \
        bf##S[1] = *reinterpret_cast<const f16x8*>(s + 16 * 8);          \
        bf##S[2] = *reinterpret_cast<const f16x8*>(s + 32 * 8);         \
        bf##S[3] = *reinterpret_cast<const f16x8*>(s + 48 * 8);          \
    }
    DEF_LOADB(0); DEF_LOADB(1);
#undef DEF_LOADB

#define DEF_WRITEA(S)                                                    \
    auto writeA##S = [&](int buf) {                                      \
        _Float16* As = smem[buf];                                        \
        union { h16x2 h2[4]; f16x8 h8; } cv;                             \
        cv.h2[0] = __builtin_amdgcn_cvt_pkrtz(areg##S[0].x, areg##S[0].y); \
        cv.h2[1] = __builtin_amdgcn_cvt_pkrtz(areg##S[0].z, areg##S[0].w); \
        cv.h2[2] = __builtin_amdgcn_cvt_pkrtz(areg##S[1].x, areg##S[1].y); \
        cv.h2[3] = __builtin_amdgcn_cvt_pkrtz(areg##S[1].z, areg##S[1].w); \
        *reinterpret_cast<f16x8*>(As + wa0) = cv.h8;                     \
        cv.h2[0] = __builtin_amdgcn_cvt_pkrtz(areg##S[2].x, areg##S[2].y); \
        cv.h2[1] = __builtin_amdgcn_cvt_pkrtz(areg##S[2].z, areg##S[2].w); \
        cv.h2[2] = __builtin_amdgcn_cvt_pkrtz(areg##S[3].x, areg##S[3].y); \
        cv.h2[3] = __builtin_amdgcn_cvt_pkrtz(areg##S[3].z, areg##S[3].w); \
        *reinterpret_cast<f16x8*>(As + wa1) = cv.h8;                     \
    }
    DEF_WRITEA(0); DEF_WRITEA(1); DEF_WRITEA(2);
#undef DEF_WRITEA

    auto compute = [&](const _Float16* As, const f16x8* bf) {
        f16x8 af[4];
#pragma unroll
        for (int mi = 0; mi < 4; ++mi)
            af[mi] = *reinterpret_cast<const f16x8*>(As + afo + mi * 128);
        __builtin_amdgcn_s_setprio(1);
#pragma unroll
        for (int mi = 0; mi < 4; ++mi)
#pragma unroll
            for (int ni = 0; ni < 4; ++ni)
                acc[mi][ni] = __builtin_amdgcn_mfma_f32_16x16x32_f16(
                    af[mi], bf[ni], acc[mi][ni], 0, 0, 0);
        __builtin_amdgcn_s_setprio(0);
    };

    // Phase kt: loadB(kt+1) FIRST (pinned), then loadA(kt+3), then ds_write
    // A(kt+1) (vm-slack 2 phases); barrier; compute buf kt%3 with B set kt&1.
#define PHASE(KT, S, WS, BS, CBS, RBUF, WBUF)                            \
    do {                                                                 \
        int ka = (KT) + 3 < 64 ? (KT) + 3 : 63;                          \
        int kb = (KT) + 1 < 64 ? (KT) + 1 : 63;                          \
        loadB##BS(kb);                                                   \
        __builtin_amdgcn_sched_barrier(0);                               \
        loadA##S(ka);                                                    \
        writeA##WS(WBUF);                                                \
        FENCE_LDS_BARRIER();                                             \
        compute(smem[RBUF], bf##CBS);                                    \
    } while (0)

    // prologue: tiles 0,1,2 -> sets 0,1,2; B tile0 -> bf0; tile0 -> buf0
    loadB0(0);
    __builtin_amdgcn_sched_barrier(0);
    loadA0(0);
    loadA1(1);
    loadA2(2);
    writeA0(0);
    FENCE_LDS_BARRIER();

    for (int kt6 = 0; kt6 < 10; ++kt6) {
        int kt = kt6 * 6;
        PHASE(kt + 0, 0, 1, 1, 0, 0, 1);
        PHASE(kt + 1, 1, 2, 0, 1, 1, 2);
        PHASE(kt + 2, 2, 0, 1, 0, 2, 0);
        PHASE(kt + 3, 0, 1, 0, 1, 0, 1);
        PHASE(kt + 4, 1, 2, 1, 0, 1, 2);
        PHASE(kt + 5, 2, 0, 0, 1, 2, 0);
    }
    PHASE(60, 0, 1, 1, 0, 0, 1);
    PHASE(61, 1, 2, 0, 1, 1, 2);
    PHASE(62, 2, 0, 1, 0, 2, 0);
    PHASE(63, 0, 1, 0, 1, 0, 1);
#undef PHASE

    // Epilogue: x = acc + be[n] + dec[b][n]; t = tanh(x); rowsum += t*wa[n]
    float rsum[4][4];
#pragma unroll
    for (int mi = 0; mi < 4; ++mi)
#pragma unroll
        for (int j = 0; j < 4; ++j) rsum[mi][j] = 0.f;

    int nb = ntile * 128 + wn * 64;
    int rb = mtile * 128 + wm * 64;
#pragma unroll
    for (int ni = 0; ni < 4; ++ni) {
        int n = nb + ni * 16 + l15;
        float wav = wa[n];
        float bev = be[n];
#pragma unroll
        for (int mi = 0; mi < 4; ++mi) {
#pragma unroll
            for (int j = 0; j < 4; ++j) {
                int row = rb + mi * 16 + lg * 4 + j;    // C/D: col=lane&15, row=(lane>>4)*4+reg
                int b = row / L_;
                float x = acc[mi][ni][j] + bev + dec[b * ATT_ + n];
                float e = __expf(2.0f * x);
                float t = 1.0f - 2.0f / (e + 1.0f);     // tanh(x), inf-safe
                rsum[mi][j] += t * wav;
            }
        }
    }
#pragma unroll
    for (int mi = 0; mi < 4; ++mi) {
#pragma unroll
        for (int j = 0; j < 4; ++j) {
            float v = rsum[mi][j];
            v += __shfl_xor(v, 1);
            v += __shfl_xor(v, 2);
            v += __shfl_xor(v, 4);
            v += __shfl_xor(v, 8);
            if (l15 == 0) red[wn][wm * 64 + mi * 16 + lg * 4 + j] = v;
        }
    }
    __syncthreads();
    if (tid < 128)
        partial[(size_t)ntile * M_ + mtile * 128 + tid] = red[0][tid] + red[1][tid];
}

// softmax over L per batch row. ba cancels in softmax -> skipped.
__global__ void softmax_kernel(const float* __restrict__ partial, float* __restrict__ alphas) {
    int b = blockIdx.x, t = threadIdx.x;     // 128 blocks x 256 threads
    int lane = t & 63, wid = t >> 6;
    __shared__ float red[4];
    float s = 0.f, val = -1e30f;
    if (t < L_) {
        int r = b * L_ + t;
        s = partial[r] + partial[M_ + r] + partial[2 * M_ + r] + partial[3 * M_ + r];
        val = s;
    }
    float m = val;
#pragma unroll
    for (int off = 1; off < 64; off <<= 1) m = fmaxf(m, __shfl_xor(m, off));
    if (lane == 0) red[wid] = m;
    __syncthreads();
    m = fmaxf(fmaxf(red[0], red[1]), fmaxf(red[2], red[3]));
    float e = (t < L_) ? __expf(s - m) : 0.f;
    float sum = e;
#pragma unroll
    for (int off = 1; off < 64; off <<= 1) sum += __shfl_xor(sum, off);
    __syncthreads();
    if (lane == 0) red[wid] = sum;
    __syncthreads();
    sum = red[0] + red[1] + red[2] + red[3];
    if (t < L_) alphas[b * L_ + t] = e / sum;
}

// context[b][e] = sum_l alphas[b][l] * enc[b][l][e]   (memory-bound pass)
__global__ void context_kernel(const float* __restrict__ enc, const float* __restrict__ alphas,
                               float* __restrict__ ctx) {
    int b = blockIdx.x >> 2;                  // 128 b x 4 e-chunks = 512 blocks
    int ec = blockIdx.x & 3;
    int e = ec * 512 + threadIdx.x * 2;
    const float* ep = enc + (size_t)b * L_ * ENC_ + e;
    const float* ap = alphas + b * L_;
    float ax = 0.f, ay = 0.f;
#pragma unroll 4
    for (int l = 0; l < L_; ++l) {
        float a = ap[l];
        float2 v = *reinterpret_cast<const float2*>(ep + (size_t)l * ENC_);
        ax += a * v.x;
        ay += a * v.y;
    }
    float2 r; r.x = ax; r.y = ay;
    *reinterpret_cast<float2*>(&ctx[b * ENC_ + e]) = r;
}

extern "C" void kernel_launch(void* const* d_in, const int* in_sizes, int n_in,
                              void* d_out, int out_size, void* d_ws, size_t ws_size,
                              hipStream_t stream) {
    const float* enc = (const float*)d_in[0];
    const float* dh  = (const float*)d_in[1];
    const float* We  = (const float*)d_in[2];
    const float* be  = (const float*)d_in[3];
    const float* Wd  = (const float*)d_in[4];
    const float* bd  = (const float*)d_in[5];
    const float* wa  = (const float*)d_in[6];
    // d_in[7] = ba: shifts all scores equally -> cancels in softmax, unused.

    float* out    = (float*)d_out;
    float* ctx    = out;               // [128][2048]
    float* alphas = out + B_ * ENC_;   // [128][196]

    char* ws = (char*)d_ws;
    float*    dec     = (float*)ws;                            // 256 KiB
    _Float16* WeTs    = (_Float16*)(ws + 262144);              // 2 MiB
    float*    partial = (float*)(ws + 262144 + 2097152);       // 392 KiB

    hipLaunchKernelGGL(wets_kernel,       dim3(512),  dim3(256), 0, stream, We, WeTs);
    hipLaunchKernelGGL(decmap_kernel,     dim3(128),  dim3(512), 0, stream, dh, Wd, bd, dec);
    hipLaunchKernelGGL(gemm_score_kernel, dim3(784),  dim3(256), 0, stream, enc, WeTs, be, wa, dec, partial);
    hipLaunchKernelGGL(softmax_kernel,    dim3(128),  dim3(256), 0, stream, partial, alphas);
    hipLaunchKernelGGL(context_kernel,    dim3(512),  dim3(256), 0, stream, enc, alphas, ctx);
}

// Round 15
// 143.249 us; speedup vs baseline: 1.1581x; 1.1581x over previous
//
#include <hip/hip_runtime.h>

#define B_   128
#define L_   196
#define ENC_ 2048
#define DEC_ 512
#define ATT_ 512
#define M_   (B_ * L_)   // 25088

typedef _Float16 f16x4 __attribute__((ext_vector_type(4)));
typedef _Float16 f16x8 __attribute__((ext_vector_type(8)));
typedef __fp16   h16x2 __attribute__((ext_vector_type(2)));
typedef float    f32x4 __attribute__((ext_vector_type(4)));

// Raw barrier: order LDS ops (lgkmcnt) but do NOT drain vmcnt -> global
// prefetches stay in flight across the barrier.
#define FENCE_LDS_BARRIER()                                        \
    do {                                                           \
        asm volatile("s_waitcnt lgkmcnt(0)" ::: "memory");         \
        __builtin_amdgcn_s_barrier();                              \
        __builtin_amdgcn_sched_barrier(0);                         \
    } while (0)

// ---------------- ws layout ----------------
// [0,          262144)   dec_map  f32 [128][512]
// [262144,    2359296)   WeTs     f16 tiled: [ntile=4][kt=64][k8=4][row=128] x f16x8 unit
// [2359296,   2459648)   scores   f32 [25088]

// We [2048][512] fp32 -> WeTs tiled-f16. Unit (nt,kt,k8,row) holds
// We[kt*32+k8*8+j][nt*128+row] for j=0..7.
__global__ void wets_kernel(const float* __restrict__ We, _Float16* __restrict__ WeTs) {
    int u = blockIdx.x * 256 + threadIdx.x;     // 131072 units
    int row = u & 127;
    int k8  = (u >> 7) & 3;
    int kt  = (u >> 9) & 63;
    int nt  = u >> 15;
    int n  = nt * 128 + row;
    int k0 = kt * 32 + k8 * 8;
    f16x8 h;
#pragma unroll
    for (int j = 0; j < 8; ++j) h[j] = (_Float16)We[(k0 + j) * ATT_ + n];
    *reinterpret_cast<f16x8*>(WeTs + (size_t)u * 8) = h;
}

// dec_map[b][a] = decoder_hidden[b] . Wd[:,a] + bd[a]
__global__ void decmap_kernel(const float* __restrict__ dh, const float* __restrict__ Wd,
                              const float* __restrict__ bd, float* __restrict__ dec) {
    int b = blockIdx.x;       // 128
    int a = threadIdx.x;      // 512
    float acc = bd[a];
    const float* dhp = dh + b * DEC_;
#pragma unroll 8
    for (int k = 0; k < DEC_; ++k) acc += dhp[k] * Wd[k * ATT_ + a];
    dec[b * ATT_ + a] = acc;
}

// Fused GEMM: 128x512 tile (FULL N per block -> A crosses L2 once, not 4x;
// R8-R14's 128x128 tiling was L2-BW-bound at ~55 B/cy/CU with A counted 4x).
// 512 threads, 8 waves (2 wm x 4 wn), each wave 64x128 (4 mi x 8 ni frags),
// acc = 128 f32/thread. Grid = 196 blocks <= 256 CUs: SINGLE round, no tail.
// A: 3-deep reg pipeline (areg0/1/2) + 3 LDS bufs (swizzled); B: 2-deep
// global(L2)->reg (bf0/1), issued B-FIRST (pinned) so the MFMA's in-order
// vmcnt wait on B never drains same-phase A loads. lgkm-only barriers.
// launch_bounds(512,1): ~240 regs (128 acc + ~110 arch) needs the 256 cap.
__global__ __launch_bounds__(512, 1)
void gemm_score_kernel(const float* __restrict__ enc,
                       const _Float16* __restrict__ WeTs,
                       const float* __restrict__ be,
                       const float* __restrict__ wa,
                       const float* __restrict__ dec,
                       float* __restrict__ scores) {
    __shared__ _Float16 smem[3][4096];   // A: [buf][(k8*128+row)*8], 8KB each
    __shared__ float red[4][128];

    int mtile = blockIdx.x;                          // 0..195, no swizzle needed
    int tid  = threadIdx.x;
    int lane = tid & 63, wid = tid >> 6;             // 8 waves
    int wm = wid >> 2, wn = wid & 3;                 // 2 x 4
    int l15 = lane & 15, lg = lane >> 4;

    // A staging: thread -> (row = tid>>2 in 0..127, c8 = tid&3), 8 fp32 each
    int arowi = tid >> 2;
    int ac8   = tid & 3;
    const float* ag = enc + (size_t)(mtile * 128 + arowi) * ENC_ + ac8 * 8;
    int wa0 = (ac8 * 128 + (arowi ^ (2 * ac8))) * 8;   // swizzled A unit

    // B fragment source: ntile = wn, row-in-tile = ni*16+l15, k8 = lg
    const _Float16* bfr = WeTs +
        ((size_t)wn * 64 * 4 * 128 + (size_t)lg * 128 + l15) * 8;
    // per-kt stride: 4096 halves; per-ni stride: 128 halves

    // A frag read half-offset (row_a = wm*64 + mi*16 + l15, swizzled)
    int afo = (lg * 128 + wm * 64 + (l15 ^ (2 * lg))) * 8;

    // staging register sets — statically named (rule #20)
    float4 areg0[2], areg1[2], areg2[2];
    f16x8  bf0[8], bf1[8];

    f32x4 acc[4][8];
#pragma unroll
    for (int mi = 0; mi < 4; ++mi)
#pragma unroll
        for (int ni = 0; ni < 8; ++ni) acc[mi][ni] = (f32x4){0.f, 0.f, 0.f, 0.f};

#define DEF_LOADA(S)                                                     \
    auto loadA##S = [&](int kt) {                                        \
        const float* a0 = ag + kt * 32;                                  \
        areg##S[0] = *reinterpret_cast<const float4*>(a0);               \
        areg##S[1] = *reinterpret_cast<const float4*>(a0 + 4);           \
    }
    DEF_LOADA(0); DEF_LOADA(1); DEF_LOADA(2);
#undef DEF_LOADA

#define DEF_LOADB(S)                                                     \
    auto loadB##S = [&](int kt) {                                        \
        const _Float16* s = bfr + (size_t)kt * 4096;                     \
        bf##S[0] = *reinterpret_cast<const f16x8*>(s + 0 * 128);         \
        bf##S[1] = *reinterpret_cast<const f16x8*>(s + 1 * 128);         \
        bf##S[2] = *reinterpret_cast<const f16x8*>(s + 2 * 128);         \
        bf##S[3] = *reinterpret_cast<const f16x8*>(s + 3 * 128);         \
        bf##S[4] = *reinterpret_cast<const f16x8*>(s + 4 * 128);         \
        bf##S[5] = *reinterpret_cast<const f16x8*>(s + 5 * 128);         \
        bf##S[6] = *reinterpret_cast<const f16x8*>(s + 6 * 128);         \
        bf##S[7] = *reinterpret_cast<const f16x8*>(s + 7 * 128);         \
    }
    DEF_LOADB(0); DEF_LOADB(1);
#undef DEF_LOADB

#define DEF_WRITEA(S)                                                    \
    auto writeA##S = [&](int buf) {                                      \
        _Float16* As = smem[buf];                                        \
        union { h16x2 h2[4]; f16x8 h8; } cv;                             \
        cv.h2[0] = __builtin_amdgcn_cvt_pkrtz(areg##S[0].x, areg##S[0].y); \
        cv.h2[1] = __builtin_amdgcn_cvt_pkrtz(areg##S[0].z, areg##S[0].w); \
        cv.h2[2] = __builtin_amdgcn_cvt_pkrtz(areg##S[1].x, areg##S[1].y); \
        cv.h2[3] = __builtin_amdgcn_cvt_pkrtz(areg##S[1].z, areg##S[1].w); \
        *reinterpret_cast<f16x8*>(As + wa0) = cv.h8;                     \
    }
    DEF_WRITEA(0); DEF_WRITEA(1); DEF_WRITEA(2);
#undef DEF_WRITEA

    auto compute = [&](const _Float16* As, const f16x8* bf) {
        f16x8 af[4];
#pragma unroll
        for (int mi = 0; mi < 4; ++mi)
            af[mi] = *reinterpret_cast<const f16x8*>(As + afo + mi * 128);
        __builtin_amdgcn_s_setprio(1);
#pragma unroll
        for (int mi = 0; mi < 4; ++mi)
#pragma unroll
            for (int ni = 0; ni < 8; ++ni)
                acc[mi][ni] = __builtin_amdgcn_mfma_f32_16x16x32_f16(
                    af[mi], bf[ni], acc[mi][ni], 0, 0, 0);
        __builtin_amdgcn_s_setprio(0);
    };

    // Phase kt: loadB(kt+1) FIRST (pinned), then loadA(kt+3), then ds_write
    // A(kt+1) (vm-slack 2 phases); barrier; compute buf kt%3 with B set kt&1.
#define PHASE(KT, S, WS, BS, CBS, RBUF, WBUF)                            \
    do {                                                                 \
        int ka = (KT) + 3 < 64 ? (KT) + 3 : 63;                          \
        int kb = (KT) + 1 < 64 ? (KT) + 1 : 63;                          \
        loadB##BS(kb);                                                   \
        __builtin_amdgcn_sched_barrier(0);                               \
        loadA##S(ka);                                                    \
        writeA##WS(WBUF);                                                \
        FENCE_LDS_BARRIER();                                             \
        compute(smem[RBUF], bf##CBS);                                    \
    } while (0)

    // prologue: B(0) first; A tiles 0,1,2 -> sets 0,1,2; tile0 -> buf0
    loadB0(0);
    __builtin_amdgcn_sched_barrier(0);
    loadA0(0);
    loadA1(1);
    loadA2(2);
    writeA0(0);
    FENCE_LDS_BARRIER();

    for (int kt6 = 0; kt6 < 10; ++kt6) {
        int kt = kt6 * 6;
        PHASE(kt + 0, 0, 1, 1, 0, 0, 1);
        PHASE(kt + 1, 1, 2, 0, 1, 1, 2);
        PHASE(kt + 2, 2, 0, 1, 0, 2, 0);
        PHASE(kt + 3, 0, 1, 0, 1, 0, 1);
        PHASE(kt + 4, 1, 2, 1, 0, 1, 2);
        PHASE(kt + 5, 2, 0, 0, 1, 2, 0);
    }
    PHASE(60, 0, 1, 1, 0, 0, 1);
    PHASE(61, 1, 2, 0, 1, 1, 2);
    PHASE(62, 2, 0, 1, 0, 2, 0);
    PHASE(63, 0, 1, 0, 1, 0, 1);
#undef PHASE

    // Epilogue: x = acc + be[n] + dec[b][n]; t = tanh(x); rowsum += t*wa[n]
    // Block covers ALL 512 n-cols -> full score per row, no partials.
    float rsum[4][4];
#pragma unroll
    for (int mi = 0; mi < 4; ++mi)
#pragma unroll
        for (int j = 0; j < 4; ++j) rsum[mi][j] = 0.f;

    int rb = mtile * 128 + wm * 64;
#pragma unroll
    for (int ni = 0; ni < 8; ++ni) {
        int n = wn * 128 + ni * 16 + l15;
        float wav = wa[n];
        float bev = be[n];
#pragma unroll
        for (int mi = 0; mi < 4; ++mi) {
#pragma unroll
            for (int j = 0; j < 4; ++j) {
                int row = rb + mi * 16 + lg * 4 + j;    // C/D: col=lane&15, row=(lane>>4)*4+reg
                int b = row / L_;
                float x = acc[mi][ni][j] + bev + dec[b * ATT_ + n];
                float e = __expf(2.0f * x);
                float t = 1.0f - 2.0f / (e + 1.0f);     // tanh(x), inf-safe
                rsum[mi][j] += t * wav;
            }
        }
    }
#pragma unroll
    for (int mi = 0; mi < 4; ++mi) {
#pragma unroll
        for (int j = 0; j < 4; ++j) {
            float v = rsum[mi][j];
            v += __shfl_xor(v, 1);
            v += __shfl_xor(v, 2);
            v += __shfl_xor(v, 4);
            v += __shfl_xor(v, 8);
            if (l15 == 0) red[wn][wm * 64 + mi * 16 + lg * 4 + j] = v;
        }
    }
    __syncthreads();
    if (tid < 128)
        scores[mtile * 128 + tid] = red[0][tid] + red[1][tid] + red[2][tid] + red[3][tid];
}

// softmax over L per batch row. ba cancels in softmax -> skipped.
__global__ void softmax_kernel(const float* __restrict__ scores, float* __restrict__ alphas) {
    int b = blockIdx.x, t = threadIdx.x;     // 128 blocks x 256 threads
    int lane = t & 63, wid = t >> 6;
    __shared__ float red[4];
    float s = 0.f, val = -1e30f;
    if (t < L_) {
        s = scores[b * L_ + t];
        val = s;
    }
    float m = val;
#pragma unroll
    for (int off = 1; off < 64; off <<= 1) m = fmaxf(m, __shfl_xor(m, off));
    if (lane == 0) red[wid] = m;
    __syncthreads();
    m = fmaxf(fmaxf(red[0], red[1]), fmaxf(red[2], red[3]));
    float e = (t < L_) ? __expf(s - m) : 0.f;
    float sum = e;
#pragma unroll
    for (int off = 1; off < 64; off <<= 1) sum += __shfl_xor(sum, off);
    __syncthreads();
    if (lane == 0) red[wid] = sum;
    __syncthreads();
    sum = red[0] + red[1] + red[2] + red[3];
    if (t < L_) alphas[b * L_ + t] = e / sum;
}

// context[b][e] = sum_l alphas[b][l] * enc[b][l][e]   (memory-bound pass)
__global__ void context_kernel(const float* __restrict__ enc, const float* __restrict__ alphas,
                               float* __restrict__ ctx) {
    int b = blockIdx.x >> 2;                  // 128 b x 4 e-chunks = 512 blocks
    int ec = blockIdx.x & 3;
    int e = ec * 512 + threadIdx.x * 2;
    const float* ep = enc + (size_t)b * L_ * ENC_ + e;
    const float* ap = alphas + b * L_;
    float ax = 0.f, ay = 0.f;
#pragma unroll 4
    for (int l = 0; l < L_; ++l) {
        float a = ap[l];
        float2 v = *reinterpret_cast<const float2*>(ep + (size_t)l * ENC_);
        ax += a * v.x;
        ay += a * v.y;
    }
    float2 r; r.x = ax; r.y = ay;
    *reinterpret_cast<float2*>(&ctx[b * ENC_ + e]) = r;
}

extern "C" void kernel_launch(void* const* d_in, const int* in_sizes, int n_in,
                              void* d_out, int out_size, void* d_ws, size_t ws_size,
                              hipStream_t stream) {
    const float* enc = (const float*)d_in[0];
    const float* dh  = (const float*)d_in[1];
    const float* We  = (const float*)d_in[2];
    const float* be  = (const float*)d_in[3];
    const float* Wd  = (const float*)d_in[4];
    const float* bd  = (const float*)d_in[5];
    const float* wa  = (const float*)d_in[6];
    // d_in[7] = ba: shifts all scores equally -> cancels in softmax, unused.

    float* out    = (float*)d_out;
    float* ctx    = out;               // [128][2048]
    float* alphas = out + B_ * ENC_;   // [128][196]

    char* ws = (char*)d_ws;
    float*    dec     = (float*)ws;                            // 256 KiB
    _Float16* WeTs    = (_Float16*)(ws + 262144);              // 2 MiB
    float*    scores  = (float*)(ws + 262144 + 2097152);       // 98 KiB

    hipLaunchKernelGGL(wets_kernel,       dim3(512),  dim3(256), 0, stream, We, WeTs);
    hipLaunchKernelGGL(decmap_kernel,     dim3(128),  dim3(512), 0, stream, dh, Wd, bd, dec);
    hipLaunchKernelGGL(gemm_score_kernel, dim3(196),  dim3(512), 0, stream, enc, WeTs, be, wa, dec, scores);
    hipLaunchKernelGGL(softmax_kernel,    dim3(128),  dim3(256), 0, stream, scores, alphas);
    hipLaunchKernelGGL(context_kernel,    dim3(512),  dim3(256), 0, stream, enc, alphas, ctx);
}